// Round 17
// baseline (99.081 us; speedup 1.0000x reference)
//
#include <hip/hip_runtime.h>

// NestedAttention MI355X round 17: T15 rotated pipeline in attn — iteration
// computes QK(t+1) (matrix pipe) BEFORE finishing step t (exp/pack/l on VALU
// + PV), so the two pipes overlap within one wave. Two named S sets (sA/sB),
// hand-unrolled x2. Base = round 16 (4-way key-split, 2592x4-wave, tree
// combine). Other kernels unchanged.
//
// ws layout (ushort elems):
//   Qf  [3i][4b][72 t][4 f][512]     @ OQ
//   Kf  [3i][4b][72 t][4 f][512]     @ OK_
//   Vf  [3i][4b][72 t][2c][2rb][512] @ OV
//   combjf [3j][4b][72 nt][12 ks][512] @ OC (+j*CSTR)  (B-frag chunks)
//   xf  [4b][72 nb][16 ks][512]      @ OXF
//   Wf  [9 s][16 ks][2 rb][512]      @ OWF
//   WoF [12 ks][8 rb][512]           @ OWOF
// Frag chunk: chunk[lane*8+e] = Op[idx=lane&31][k=8*(lane>>5)+e]

#define BB 4
#define CC 256
#define NN_ 2304
#define RR 64

#define OQ 0
#define OK_ 1769472
#define OV 3538944
#define OC 5308416
#define CSTR 1769472
#define FR_IB 147456
#define OXF 10616832
#define OWF 12976128
#define OWOF 13123584

typedef __bf16 bf16x8 __attribute__((ext_vector_type(8)));
typedef float f32x16 __attribute__((ext_vector_type(16)));
typedef unsigned short ushort8 __attribute__((ext_vector_type(8)));
typedef unsigned int uintx2 __attribute__((ext_vector_type(2)));
typedef unsigned int uintx4 __attribute__((ext_vector_type(4)));

#if __has_builtin(__builtin_amdgcn_exp2f)
#define EXP2(x) __builtin_amdgcn_exp2f(x)
#else
#define EXP2(x) exp2f(x)
#endif

__device__ __forceinline__ float bf2f(unsigned short s) {
    unsigned int u = ((unsigned int)s) << 16;
    return __builtin_bit_cast(float, u);
}
__device__ __forceinline__ unsigned int pk_bf16(float lo, float hi) {
    unsigned int r;
    asm("v_cvt_pk_bf16_f32 %0, %1, %2" : "=v"(r) : "v"(lo), "v"(hi));
    return r;
}

// ---------------------------------------------------------------------------
// Prep: bid<9 weights->A-frags; bid<12 wo->A-frags; else x->B-frags.
// ---------------------------------------------------------------------------
__global__ __launch_bounds__(256) void prep_kernel(
    const float* __restrict__ x, const float* __restrict__ wq,
    const float* __restrict__ wk, const float* __restrict__ wv,
    const float* __restrict__ wo, unsigned short* __restrict__ wsb)
{
    int bid = blockIdx.x;
    int t = threadIdx.x;
    if (bid < 9) {
        int s = bid;
        int type = s / 3, i = s % 3;
        const float* wsel = (type == 0) ? wq : (type == 1 ? wk : wv);
        const float scale = (type == 0) ? 0.18033688011112042f : 1.0f;  // 0.125*log2e
        unsigned short* dst = wsb + OWF + s * 16384;
        #pragma unroll
        for (int p = 0; p < 8; ++p) {
            int u = t + 256 * p;
            int ks = u >> 7, rb = (u >> 6) & 1, lo = u & 63;
            int row = rb * 32 + (lo & 31), c = ks * 16 + 8 * (lo >> 5);
            const float* src = wsel + ((i * 64 + row) * 256 + c);
            float4 f0 = *(const float4*)(src);
            float4 f1 = *(const float4*)(src + 4);
            uintx4 pwv = {pk_bf16(f0.x * scale, f0.y * scale),
                          pk_bf16(f0.z * scale, f0.w * scale),
                          pk_bf16(f1.x * scale, f1.y * scale),
                          pk_bf16(f1.z * scale, f1.w * scale)};
            *(uintx4*)(dst + (ks * 2 + rb) * 512 + lo * 8) = pwv;
        }
        return;
    }
    if (bid < 12) {
        int bb = bid - 9;
        #pragma unroll
        for (int p = 0; p < 8; ++p) {
            int u = t + 256 * p;
            int cg = bb * 32 + (u >> 6);
            int lane = u & 63;
            int ks = cg >> 3, rb = cg & 7;
            int row = rb * 32 + (lane & 31);
            int g = ks * 16 + 8 * (lane >> 5);
            const float* src = wo + row * 192 + g;
            float4 f0 = *(const float4*)(src);
            float4 f1 = *(const float4*)(src + 4);
            uintx4 pwv = {pk_bf16(f0.x, f0.y), pk_bf16(f0.z, f0.w),
                          pk_bf16(f1.x, f1.y), pk_bf16(f1.z, f1.w)};
            *(uintx4*)(wsb + OWOF + cg * 512 + lane * 8) = pwv;
        }
        return;
    }
    __shared__ __align__(16) float xs[64 * 132];
    int xb = bid - 12;
    int cq  = xb & 3;
    int nt2 = (xb >> 2) % 18;
    int b   = xb / 72;
    int c0 = cq * 64, n0 = nt2 * 128;
    #pragma unroll
    for (int p = 0; p < 8; ++p) {
        int u = t + 256 * p;
        int cl = u >> 5, nq = (u & 31) * 4;
        *(float4*)&xs[cl * 132 + nq] =
            *(const float4*)&x[((size_t)(b * CC + c0 + cl)) * NN_ + n0 + nq];
    }
    __syncthreads();
    unsigned short* xfb = wsb + OXF + ((size_t)b) * 72 * 16 * 512;
    #pragma unroll
    for (int p = 0; p < 4; ++p) {
        int u = t + 256 * p;
        int nb_l = u >> 8, ks_l = (u >> 6) & 3, lo = u & 63;
        int hh = lo >> 5, idx = lo & 31;
        int clb = ks_l * 16 + 8 * hh;
        int nn = nb_l * 32 + idx;
        unsigned int pw[4];
        #pragma unroll
        for (int d = 0; d < 4; ++d) {
            float a  = xs[(clb + 2 * d) * 132 + nn];
            float bb2 = xs[(clb + 2 * d + 1) * 132 + nn];
            pw[d] = pk_bf16(a, bb2);
        }
        int nb = nt2 * 4 + nb_l, ks = cq * 4 + ks_l;
        *(uintx4*)(xfb + (nb * 16 + ks) * 512 + lo * 8) =
            (uintx4){pw[0], pw[1], pw[2], pw[3]};
    }
}

// ---------------------------------------------------------------------------
// Kernel: MFMA projection (unchanged structure).
// ---------------------------------------------------------------------------
__global__ __launch_bounds__(256) void proj_mfma(unsigned short* __restrict__ wsb)
{
    int bid = blockIdx.x;
    int s = bid / 72;
    int rem = bid % 72;
    int b = rem / 18, nb4 = rem % 18;
    int type = s / 3, i = s % 3;
    int t = threadIdx.x;
    int w = t >> 6, lane = t & 63;
    int lq = lane & 31, h = lane >> 5;
    int nb = nb4 * 4 + w;

    const unsigned short* wf = wsb + OWF + s * 16384 + lane * 8;
    const unsigned short* xf = wsb + OXF + ((size_t)(b * 72 + nb) * 16) * 512 + lane * 8;

    f32x16 o0 = {}, o1 = {};
    if (type < 2) {
        #pragma unroll
        for (int ks = 0; ks < 16; ++ks) {
            bf16x8 a0 = *(const bf16x8*)(wf + ks * 1024);
            bf16x8 a1 = *(const bf16x8*)(wf + ks * 1024 + 512);
            bf16x8 bx = *(const bf16x8*)(xf + ks * 512);
            o0 = __builtin_amdgcn_mfma_f32_32x32x16_bf16(a0, bx, o0, 0, 0, 0);
            o1 = __builtin_amdgcn_mfma_f32_32x32x16_bf16(a1, bx, o1, 0, 0, 0);
        }
    } else {
        #pragma unroll
        for (int ks = 0; ks < 16; ++ks) {
            bf16x8 a0 = *(const bf16x8*)(wf + ks * 1024);
            bf16x8 a1 = *(const bf16x8*)(wf + ks * 1024 + 512);
            bf16x8 bx = *(const bf16x8*)(xf + ks * 512);
            o0 = __builtin_amdgcn_mfma_f32_32x32x16_bf16(bx, a0, o0, 0, 0, 0);
            o1 = __builtin_amdgcn_mfma_f32_32x32x16_bf16(bx, a1, o1, 0, 0, 0);
        }
    }

    unsigned short* dstbase =
        wsb + ((type == 0) ? OQ : (type == 1 ? OK_ : OV)) +
        ((size_t)(i * 4 + b)) * FR_IB + nb * 2048;

    if (type < 2) {
        #pragma unroll
        for (int g = 0; g < 4; ++g) {
            int kd = 8 * g + 4 * h;
            int off = (kd >> 4) * 512 + ((kd >> 3) & 1) * 256 + lq * 8 + (kd & 7);
            *(uintx2*)(dstbase + off) =
                (uintx2){pk_bf16(o0[4 * g], o0[4 * g + 1]),
                         pk_bf16(o0[4 * g + 2], o0[4 * g + 3])};
            int kd2 = kd + 32;
            int off2 = (kd2 >> 4) * 512 + ((kd2 >> 3) & 1) * 256 + lq * 8 + (kd2 & 7);
            *(uintx2*)(dstbase + off2) =
                (uintx2){pk_bf16(o1[4 * g], o1[4 * g + 1]),
                         pk_bf16(o1[4 * g + 2], o1[4 * g + 3])};
        }
    } else {
        #pragma unroll
        for (int g = 0; g < 4; ++g) {
            int off = (g >> 1) * 1024 + (g & 1) * 256 + lq * 8 + 4 * h;
            *(uintx2*)(dstbase + off) =
                (uintx2){pk_bf16(o0[4 * g], o0[4 * g + 1]),
                         pk_bf16(o0[4 * g + 2], o0[4 * g + 3])};
            *(uintx2*)(dstbase + off + 512) =
                (uintx2){pk_bf16(o1[4 * g], o1[4 * g + 1]),
                         pk_bf16(o1[4 * g + 2], o1[4 * g + 3])};
        }
    }
}

// ---------------------------------------------------------------------------
// Kernel: barrier-free MFMA flash attention, 4-way key-split, T15 rotated
// pipeline: QK(t+1) issues before finish(t); exp/pack/PV of t overlap the
// matrix-pipe drain of t+1. Single reload-in-place K set; V JIT in finish.
// Combine: 2-slot LDS tree (fp32 exact).
// ---------------------------------------------------------------------------
__global__ __launch_bounds__(256, 4) void attn_kernel(unsigned short* __restrict__ wsb)
{
    __shared__ __align__(16) float fl[4224];  // 2 slots x 2112 = 16.9KB

    int bid = blockIdx.x;
    int wid = (bid & 7) * 324 + (bid >> 3);   // XCD-bijective (2592 = 8*324)
    int s12 = wid / 216;                      // (j,b) reuse set
    int rem = wid % 216;
    int j = s12 >> 2, b = s12 & 3;
    int i = rem / 72;
    int qp = rem % 72;
    int w = threadIdx.x >> 6;                 // key-quarter 0..3
    int lane = threadIdx.x & 63;
    int lq = lane & 31;
    int h = lane >> 5;
    int q0 = qp * 32;

    const unsigned short* qtf = wsb + OQ + ((size_t)(i * 4 + b)) * FR_IB +
                                qp * 2048 + lane * 8;
    const unsigned short* kp = wsb + OK_ + ((size_t)(j * 4 + b)) * FR_IB +
                               (size_t)(w * 18) * 2048 + lane * 8;
    const unsigned short* vp = wsb + OV + ((size_t)(j * 4 + b)) * FR_IB +
                               (size_t)(w * 18) * 2048 + lane * 8;

    bf16x8 bq0 = *(const bf16x8*)(qtf + 0);
    bf16x8 bq1 = *(const bf16x8*)(qtf + 512);
    bf16x8 bq2 = *(const bf16x8*)(qtf + 1024);
    bf16x8 bq3 = *(const bf16x8*)(qtf + 1536);

    f32x16 o0 = {}, o1 = {};
    float l_loc = 0.f;

    // finish step `vstep` whose scores are in s: exp, l, pack, PV (V JIT)
    auto finish = [&](f32x16& s, int vstep) {
        const unsigned short* vb = vp + (size_t)vstep * 2048;
        bf16x8 v00 = *(const bf16x8*)(vb + 0 * 512);  // c0,rb0
        bf16x8 v10 = *(const bf16x8*)(vb + 1 * 512);  // c0,rb1
        bf16x8 v01 = *(const bf16x8*)(vb + 2 * 512);  // c1,rb0
        bf16x8 v11 = *(const bf16x8*)(vb + 3 * 512);  // c1,rb1

        // raw v_exp_f32 — inputs bounded (|S|log2e <= ~12)
        #pragma unroll
        for (int r = 0; r < 16; ++r) s[r] = EXP2(s[r]);
        l_loc += ((s[0] + s[1]) + (s[2] + s[3])) + ((s[4] + s[5]) + (s[6] + s[7])) +
                 ((s[8] + s[9]) + (s[10] + s[11])) + ((s[12] + s[13]) + (s[14] + s[15]));

        {   // keys 0..15
            unsigned int a0 = pk_bf16(s[0], s[1]);
            unsigned int a1 = pk_bf16(s[2], s[3]);
            unsigned int b0 = pk_bf16(s[4], s[5]);
            unsigned int b1 = pk_bf16(s[6], s[7]);
            uintx2 r0 = __builtin_amdgcn_permlane32_swap(a0, b0, false, false);
            uintx2 r1 = __builtin_amdgcn_permlane32_swap(a1, b1, false, false);
            uintx4 pwv = {r0[0], r1[0], r0[1], r1[1]};
            bf16x8 pa = __builtin_bit_cast(bf16x8, pwv);
            o0 = __builtin_amdgcn_mfma_f32_32x32x16_bf16(v00, pa, o0, 0, 0, 0);
            o1 = __builtin_amdgcn_mfma_f32_32x32x16_bf16(v10, pa, o1, 0, 0, 0);
        }
        {   // keys 16..31
            unsigned int a0 = pk_bf16(s[8], s[9]);
            unsigned int a1 = pk_bf16(s[10], s[11]);
            unsigned int b0 = pk_bf16(s[12], s[13]);
            unsigned int b1 = pk_bf16(s[14], s[15]);
            uintx2 r0 = __builtin_amdgcn_permlane32_swap(a0, b0, false, false);
            uintx2 r1 = __builtin_amdgcn_permlane32_swap(a1, b1, false, false);
            uintx4 pwv = {r0[0], r1[0], r0[1], r1[1]};
            bf16x8 pa = __builtin_bit_cast(bf16x8, pwv);
            o0 = __builtin_amdgcn_mfma_f32_32x32x16_bf16(v01, pa, o0, 0, 0, 0);
            o1 = __builtin_amdgcn_mfma_f32_32x32x16_bf16(v11, pa, o1, 0, 0, 0);
        }
    };

    // ---- prologue: K(0) -> QK(0) into sA; then K(1) resident ----
    bf16x8 k0 = *(const bf16x8*)(kp + 0 * 512);
    bf16x8 k1 = *(const bf16x8*)(kp + 1 * 512);
    bf16x8 k2 = *(const bf16x8*)(kp + 2 * 512);
    bf16x8 k3 = *(const bf16x8*)(kp + 3 * 512);
    f32x16 sA, sB;
    {
        f32x16 z = {};
        sA = __builtin_amdgcn_mfma_f32_32x32x16_bf16(k0, bq0, z, 0, 0, 0);
        sA = __builtin_amdgcn_mfma_f32_32x32x16_bf16(k1, bq1, sA, 0, 0, 0);
        sA = __builtin_amdgcn_mfma_f32_32x32x16_bf16(k2, bq2, sA, 0, 0, 0);
        sA = __builtin_amdgcn_mfma_f32_32x32x16_bf16(k3, bq3, sA, 0, 0, 0);
    }
    {
        const unsigned short* kb = kp + 2048;
        k0 = *(const bf16x8*)(kb + 0 * 512);
        k1 = *(const bf16x8*)(kb + 1 * 512);
        k2 = *(const bf16x8*)(kb + 2 * 512);
        k3 = *(const bf16x8*)(kb + 3 * 512);
    }

    // ---- rotated main loop: 9 double-iterations = 18 finishes ----
    for (int t = 0; t < 18; t += 2) {
        // QK(t+1) into sB (k holds K(t+1))
        {
            f32x16 z = {};
            sB = __builtin_amdgcn_mfma_f32_32x32x16_bf16(k0, bq0, z, 0, 0, 0);
            sB = __builtin_amdgcn_mfma_f32_32x32x16_bf16(k1, bq1, sB, 0, 0, 0);
            sB = __builtin_amdgcn_mfma_f32_32x32x16_bf16(k2, bq2, sB, 0, 0, 0);
            sB = __builtin_amdgcn_mfma_f32_32x32x16_bf16(k3, bq3, sB, 0, 0, 0);
        }
        {   // reload k = K((t+2) mod 18)
            int nx = (t + 2 < 18) ? (t + 2) : 0;
            const unsigned short* kb = kp + (size_t)nx * 2048;
            k0 = *(const bf16x8*)(kb + 0 * 512);
            k1 = *(const bf16x8*)(kb + 1 * 512);
            k2 = *(const bf16x8*)(kb + 2 * 512);
            k3 = *(const bf16x8*)(kb + 3 * 512);
        }
        finish(sA, t);          // overlaps sB's matrix-pipe drain

        // QK((t+2) mod 18) into sA (garbage on final pair — never finished)
        {
            f32x16 z = {};
            sA = __builtin_amdgcn_mfma_f32_32x32x16_bf16(k0, bq0, z, 0, 0, 0);
            sA = __builtin_amdgcn_mfma_f32_32x32x16_bf16(k1, bq1, sA, 0, 0, 0);
            sA = __builtin_amdgcn_mfma_f32_32x32x16_bf16(k2, bq2, sA, 0, 0, 0);
            sA = __builtin_amdgcn_mfma_f32_32x32x16_bf16(k3, bq3, sA, 0, 0, 0);
        }
        {   // reload k = K((t+3) mod 18)
            int nx = (t + 3 < 18) ? (t + 3) : 0;
            const unsigned short* kb = kp + (size_t)nx * 2048;
            k0 = *(const bf16x8*)(kb + 0 * 512);
            k1 = *(const bf16x8*)(kb + 1 * 512);
            k2 = *(const bf16x8*)(kb + 2 * 512);
            k3 = *(const bf16x8*)(kb + 3 * 512);
        }
        finish(sB, t + 1);      // overlaps sA's matrix-pipe drain
    }

    float l_full = l_loc + __shfl_xor(l_loc, 32);

    // ---- tree combine (fp32 exact): O = sum O_w / sum l_w ----
    if (w & 1) {
        float* sl = fl + (w >> 1) * 2112;
        #pragma unroll
        for (int reg = 0; reg < 16; ++reg) {
            sl[reg * 64 + lane] = o0[reg];
            sl[1024 + reg * 64 + lane] = o1[reg];
        }
        sl[2048 + lane] = l_full;
    }
    __syncthreads();
    if (!(w & 1)) {
        const float* sl = fl + (w >> 1) * 2112;
        #pragma unroll
        for (int reg = 0; reg < 16; ++reg) {
            o0[reg] += sl[reg * 64 + lane];
            o1[reg] += sl[1024 + reg * 64 + lane];
        }
        l_full += sl[2048 + lane];
    }
    __syncthreads();
    if (w == 2) {
        float* sl = fl;
        #pragma unroll
        for (int reg = 0; reg < 16; ++reg) {
            sl[reg * 64 + lane] = o0[reg];
            sl[1024 + reg * 64 + lane] = o1[reg];
        }
        sl[2048 + lane] = l_full;
    }
    __syncthreads();
    if (w != 0) return;

    #pragma unroll
    for (int reg = 0; reg < 16; ++reg) {
        o0[reg] += fl[reg * 64 + lane];
        o1[reg] += fl[1024 + reg * 64 + lane];
    }
    l_full += fl[2048 + lane];

    float inv = 1.f / l_full;
    o0 *= inv; o1 *= inv;

    // transpose O^T -> per-query rows (wave-0-local LDS reuse), write comb frags
    float* tw = fl;
    #pragma unroll
    for (int reg = 0; reg < 16; ++reg) {
        int rv = (reg & 3) + 8 * (reg >> 2) + 4 * h;
        tw[lq * 65 + rv] = o0[reg];
        tw[lq * 65 + 32 + rv] = o1[reg];
    }
    // chunk[lane*8+e] = comb[n=q0+(lane&31)][g = i*64 + ksl*16 + 8h + e]
    unsigned short* cb = wsb + OC + (size_t)j * CSTR +
                         ((size_t)((b * 72 + qp) * 12 + i * 4)) * 512;
    #pragma unroll
    for (int ksl = 0; ksl < 4; ++ksl) {
        const float* src = tw + lq * 65 + ksl * 16 + 8 * h;
        uintx4 pwv = {pk_bf16(src[0], src[1]), pk_bf16(src[2], src[3]),
                      pk_bf16(src[4], src[5]), pk_bf16(src[6], src[7])};
        *(uintx4*)(cb + ksl * 512 + lane * 8) = pwv;
    }
}

// ---------------------------------------------------------------------------
// Kernel: MFMA out-projection + sigmoid gate.
// ---------------------------------------------------------------------------
__global__ __launch_bounds__(256) void out_mfma(
    const float* __restrict__ x, const unsigned short* __restrict__ wsb,
    float* __restrict__ out)
{
    int bid = blockIdx.x;
    int ch = bid & 1;
    int nt = (bid >> 1) % 72;
    int b  = bid / 144;
    int n0 = nt * 32;
    int t = threadIdx.x;
    int w = t >> 6, lane = t & 63;
    int lq = lane & 31, h = lane >> 5;
    int rb = ch * 4 + w;

    const unsigned short* wof = wsb + OWOF + lane * 8;
    const unsigned short* cbase = wsb + OC +
        ((size_t)((b * 72 + nt) * 12)) * 512 + lane * 8;

    f32x16 acc = {};
    #pragma unroll
    for (int j = 0; j < 3; ++j) {
        const unsigned short* cj = cbase + (size_t)j * CSTR;
        #pragma unroll
        for (int ksx = 0; ksx < 12; ++ksx) {
            bf16x8 bx = *(const bf16x8*)(cj + ksx * 512);
            bf16x8 a0 = *(const bf16x8*)(wof + (ksx * 8 + rb) * 512);
            acc = __builtin_amdgcn_mfma_f32_32x32x16_bf16(a0, bx, acc, 0, 0, 0);
        }
    }

    int c0 = rb * 32;
    #pragma unroll
    for (int reg = 0; reg < 16; ++reg) {
        int c = c0 + (reg & 3) + 8 * (reg >> 2) + 4 * h;
        size_t idx = ((size_t)(b * CC + c)) * NN_ + n0 + lq;
        float sg = 1.f / (1.f + EXP2(acc[reg] * -1.44269504f));
        out[idx] = x[idx] * sg;
    }
}

extern "C" void kernel_launch(void* const* d_in, const int* in_sizes, int n_in,
                              void* d_out, int out_size, void* d_ws, size_t ws_size,
                              hipStream_t stream) {
    const float* x  = (const float*)d_in[0];
    const float* wq = (const float*)d_in[1];
    const float* wk = (const float*)d_in[2];
    const float* wv = (const float*)d_in[3];
    const float* wo = (const float*)d_in[4];
    unsigned short* wsb = (unsigned short*)d_ws;
    float* out = (float*)d_out;

    prep_kernel<<<300, 256, 0, stream>>>(x, wq, wk, wv, wo, wsb);
    proj_mfma<<<648, 256, 0, stream>>>(wsb);
    attn_kernel<<<2592, 256, 0, stream>>>(wsb);
    out_mfma<<<576, 256, 0, stream>>>(x, wsb, out);
}

// Round 18
// 96.133 us; speedup vs baseline: 1.0307x; 1.0307x over previous
//
#include <hip/hip_runtime.h>

// NestedAttention MI355X round 18: single-variable probe — attn at
// launch_bounds(256,3) (reg cap ~168) so the whole ~112-value frame lives in
// arch VGPRs: no v_accvgpr_read/write round-trips on s/o (suspected 2.5x
// VALU inflation under the (256,4) cap-128 split). Residency unchanged
// (~3 waves/SIMD = today's measured 10.5/CU). Everything else = round 16.
//
// ws layout (ushort elems):
//   Qf  [3i][4b][72 t][4 f][512]     @ OQ
//   Kf  [3i][4b][72 t][4 f][512]     @ OK_
//   Vf  [3i][4b][72 t][2c][2rb][512] @ OV
//   combjf [3j][4b][72 nt][12 ks][512] @ OC (+j*CSTR)  (B-frag chunks)
//   xf  [4b][72 nb][16 ks][512]      @ OXF
//   Wf  [9 s][16 ks][2 rb][512]      @ OWF
//   WoF [12 ks][8 rb][512]           @ OWOF
// Frag chunk: chunk[lane*8+e] = Op[idx=lane&31][k=8*(lane>>5)+e]

#define BB 4
#define CC 256
#define NN_ 2304
#define RR 64

#define OQ 0
#define OK_ 1769472
#define OV 3538944
#define OC 5308416
#define CSTR 1769472
#define FR_IB 147456
#define OXF 10616832
#define OWF 12976128
#define OWOF 13123584

typedef __bf16 bf16x8 __attribute__((ext_vector_type(8)));
typedef float f32x16 __attribute__((ext_vector_type(16)));
typedef unsigned short ushort8 __attribute__((ext_vector_type(8)));
typedef unsigned int uintx2 __attribute__((ext_vector_type(2)));
typedef unsigned int uintx4 __attribute__((ext_vector_type(4)));

#if __has_builtin(__builtin_amdgcn_exp2f)
#define EXP2(x) __builtin_amdgcn_exp2f(x)
#else
#define EXP2(x) exp2f(x)
#endif

__device__ __forceinline__ float bf2f(unsigned short s) {
    unsigned int u = ((unsigned int)s) << 16;
    return __builtin_bit_cast(float, u);
}
__device__ __forceinline__ unsigned int pk_bf16(float lo, float hi) {
    unsigned int r;
    asm("v_cvt_pk_bf16_f32 %0, %1, %2" : "=v"(r) : "v"(lo), "v"(hi));
    return r;
}

// ---------------------------------------------------------------------------
// Prep: bid<9 weights->A-frags; bid<12 wo->A-frags; else x->B-frags.
// ---------------------------------------------------------------------------
__global__ __launch_bounds__(256) void prep_kernel(
    const float* __restrict__ x, const float* __restrict__ wq,
    const float* __restrict__ wk, const float* __restrict__ wv,
    const float* __restrict__ wo, unsigned short* __restrict__ wsb)
{
    int bid = blockIdx.x;
    int t = threadIdx.x;
    if (bid < 9) {
        int s = bid;
        int type = s / 3, i = s % 3;
        const float* wsel = (type == 0) ? wq : (type == 1 ? wk : wv);
        const float scale = (type == 0) ? 0.18033688011112042f : 1.0f;  // 0.125*log2e
        unsigned short* dst = wsb + OWF + s * 16384;
        #pragma unroll
        for (int p = 0; p < 8; ++p) {
            int u = t + 256 * p;
            int ks = u >> 7, rb = (u >> 6) & 1, lo = u & 63;
            int row = rb * 32 + (lo & 31), c = ks * 16 + 8 * (lo >> 5);
            const float* src = wsel + ((i * 64 + row) * 256 + c);
            float4 f0 = *(const float4*)(src);
            float4 f1 = *(const float4*)(src + 4);
            uintx4 pwv = {pk_bf16(f0.x * scale, f0.y * scale),
                          pk_bf16(f0.z * scale, f0.w * scale),
                          pk_bf16(f1.x * scale, f1.y * scale),
                          pk_bf16(f1.z * scale, f1.w * scale)};
            *(uintx4*)(dst + (ks * 2 + rb) * 512 + lo * 8) = pwv;
        }
        return;
    }
    if (bid < 12) {
        int bb = bid - 9;
        #pragma unroll
        for (int p = 0; p < 8; ++p) {
            int u = t + 256 * p;
            int cg = bb * 32 + (u >> 6);
            int lane = u & 63;
            int ks = cg >> 3, rb = cg & 7;
            int row = rb * 32 + (lane & 31);
            int g = ks * 16 + 8 * (lane >> 5);
            const float* src = wo + row * 192 + g;
            float4 f0 = *(const float4*)(src);
            float4 f1 = *(const float4*)(src + 4);
            uintx4 pwv = {pk_bf16(f0.x, f0.y), pk_bf16(f0.z, f0.w),
                          pk_bf16(f1.x, f1.y), pk_bf16(f1.z, f1.w)};
            *(uintx4*)(wsb + OWOF + cg * 512 + lane * 8) = pwv;
        }
        return;
    }
    __shared__ __align__(16) float xs[64 * 132];
    int xb = bid - 12;
    int cq  = xb & 3;
    int nt2 = (xb >> 2) % 18;
    int b   = xb / 72;
    int c0 = cq * 64, n0 = nt2 * 128;
    #pragma unroll
    for (int p = 0; p < 8; ++p) {
        int u = t + 256 * p;
        int cl = u >> 5, nq = (u & 31) * 4;
        *(float4*)&xs[cl * 132 + nq] =
            *(const float4*)&x[((size_t)(b * CC + c0 + cl)) * NN_ + n0 + nq];
    }
    __syncthreads();
    unsigned short* xfb = wsb + OXF + ((size_t)b) * 72 * 16 * 512;
    #pragma unroll
    for (int p = 0; p < 4; ++p) {
        int u = t + 256 * p;
        int nb_l = u >> 8, ks_l = (u >> 6) & 3, lo = u & 63;
        int hh = lo >> 5, idx = lo & 31;
        int clb = ks_l * 16 + 8 * hh;
        int nn = nb_l * 32 + idx;
        unsigned int pw[4];
        #pragma unroll
        for (int d = 0; d < 4; ++d) {
            float a  = xs[(clb + 2 * d) * 132 + nn];
            float bb2 = xs[(clb + 2 * d + 1) * 132 + nn];
            pw[d] = pk_bf16(a, bb2);
        }
        int nb = nt2 * 4 + nb_l, ks = cq * 4 + ks_l;
        *(uintx4*)(xfb + (nb * 16 + ks) * 512 + lo * 8) =
            (uintx4){pw[0], pw[1], pw[2], pw[3]};
    }
}

// ---------------------------------------------------------------------------
// Kernel: MFMA projection (unchanged structure).
// ---------------------------------------------------------------------------
__global__ __launch_bounds__(256) void proj_mfma(unsigned short* __restrict__ wsb)
{
    int bid = blockIdx.x;
    int s = bid / 72;
    int rem = bid % 72;
    int b = rem / 18, nb4 = rem % 18;
    int type = s / 3, i = s % 3;
    int t = threadIdx.x;
    int w = t >> 6, lane = t & 63;
    int lq = lane & 31, h = lane >> 5;
    int nb = nb4 * 4 + w;

    const unsigned short* wf = wsb + OWF + s * 16384 + lane * 8;
    const unsigned short* xf = wsb + OXF + ((size_t)(b * 72 + nb) * 16) * 512 + lane * 8;

    f32x16 o0 = {}, o1 = {};
    if (type < 2) {
        #pragma unroll
        for (int ks = 0; ks < 16; ++ks) {
            bf16x8 a0 = *(const bf16x8*)(wf + ks * 1024);
            bf16x8 a1 = *(const bf16x8*)(wf + ks * 1024 + 512);
            bf16x8 bx = *(const bf16x8*)(xf + ks * 512);
            o0 = __builtin_amdgcn_mfma_f32_32x32x16_bf16(a0, bx, o0, 0, 0, 0);
            o1 = __builtin_amdgcn_mfma_f32_32x32x16_bf16(a1, bx, o1, 0, 0, 0);
        }
    } else {
        #pragma unroll
        for (int ks = 0; ks < 16; ++ks) {
            bf16x8 a0 = *(const bf16x8*)(wf + ks * 1024);
            bf16x8 a1 = *(const bf16x8*)(wf + ks * 1024 + 512);
            bf16x8 bx = *(const bf16x8*)(xf + ks * 512);
            o0 = __builtin_amdgcn_mfma_f32_32x32x16_bf16(bx, a0, o0, 0, 0, 0);
            o1 = __builtin_amdgcn_mfma_f32_32x32x16_bf16(bx, a1, o1, 0, 0, 0);
        }
    }

    unsigned short* dstbase =
        wsb + ((type == 0) ? OQ : (type == 1 ? OK_ : OV)) +
        ((size_t)(i * 4 + b)) * FR_IB + nb * 2048;

    if (type < 2) {
        #pragma unroll
        for (int g = 0; g < 4; ++g) {
            int kd = 8 * g + 4 * h;
            int off = (kd >> 4) * 512 + ((kd >> 3) & 1) * 256 + lq * 8 + (kd & 7);
            *(uintx2*)(dstbase + off) =
                (uintx2){pk_bf16(o0[4 * g], o0[4 * g + 1]),
                         pk_bf16(o0[4 * g + 2], o0[4 * g + 3])};
            int kd2 = kd + 32;
            int off2 = (kd2 >> 4) * 512 + ((kd2 >> 3) & 1) * 256 + lq * 8 + (kd2 & 7);
            *(uintx2*)(dstbase + off2) =
                (uintx2){pk_bf16(o1[4 * g], o1[4 * g + 1]),
                         pk_bf16(o1[4 * g + 2], o1[4 * g + 3])};
        }
    } else {
        #pragma unroll
        for (int g = 0; g < 4; ++g) {
            int off = (g >> 1) * 1024 + (g & 1) * 256 + lq * 8 + 4 * h;
            *(uintx2*)(dstbase + off) =
                (uintx2){pk_bf16(o0[4 * g], o0[4 * g + 1]),
                         pk_bf16(o0[4 * g + 2], o0[4 * g + 3])};
            *(uintx2*)(dstbase + off + 512) =
                (uintx2){pk_bf16(o1[4 * g], o1[4 * g + 1]),
                         pk_bf16(o1[4 * g + 2], o1[4 * g + 3])};
        }
    }
}

// ---------------------------------------------------------------------------
// Kernel: barrier-free MFMA flash attention, 4-way key-split (round-16
// structure) at launch_bounds(256,3): all live values in arch VGPRs.
// ---------------------------------------------------------------------------
__global__ __launch_bounds__(256, 3) void attn_kernel(unsigned short* __restrict__ wsb)
{
    __shared__ __align__(16) float fl[4224];  // 2 slots x 2112 = 16.9KB

    int bid = blockIdx.x;
    int wid = (bid & 7) * 324 + (bid >> 3);   // XCD-bijective (2592 = 8*324)
    int s12 = wid / 216;                      // (j,b) reuse set
    int rem = wid % 216;
    int j = s12 >> 2, b = s12 & 3;
    int i = rem / 72;
    int qp = rem % 72;
    int w = threadIdx.x >> 6;                 // key-quarter 0..3
    int lane = threadIdx.x & 63;
    int lq = lane & 31;
    int h = lane >> 5;
    int q0 = qp * 32;

    const unsigned short* qtf = wsb + OQ + ((size_t)(i * 4 + b)) * FR_IB +
                                qp * 2048 + lane * 8;
    const unsigned short* kp = wsb + OK_ + ((size_t)(j * 4 + b)) * FR_IB +
                               (size_t)(w * 18) * 2048 + lane * 8;
    const unsigned short* vp = wsb + OV + ((size_t)(j * 4 + b)) * FR_IB +
                               (size_t)(w * 18) * 2048 + lane * 8;

    bf16x8 bq0 = *(const bf16x8*)(qtf + 0);
    bf16x8 bq1 = *(const bf16x8*)(qtf + 512);
    bf16x8 bq2 = *(const bf16x8*)(qtf + 1024);
    bf16x8 bq3 = *(const bf16x8*)(qtf + 1536);

    f32x16 o0 = {}, o1 = {};
    float l_loc = 0.f;

    // one 32-key step: K frags in regs; V loaded just-in-time
    auto compute_step = [&](bf16x8 k0, bf16x8 k1, bf16x8 k2, bf16x8 k3,
                            int step) {
        const unsigned short* vb = vp + (size_t)step * 2048;
        bf16x8 v00 = *(const bf16x8*)(vb + 0 * 512);  // c0,rb0
        bf16x8 v10 = *(const bf16x8*)(vb + 1 * 512);  // c0,rb1
        bf16x8 v01 = *(const bf16x8*)(vb + 2 * 512);  // c1,rb0
        bf16x8 v11 = *(const bf16x8*)(vb + 3 * 512);  // c1,rb1

        f32x16 s = {};
        s = __builtin_amdgcn_mfma_f32_32x32x16_bf16(k0, bq0, s, 0, 0, 0);
        s = __builtin_amdgcn_mfma_f32_32x32x16_bf16(k1, bq1, s, 0, 0, 0);
        s = __builtin_amdgcn_mfma_f32_32x32x16_bf16(k2, bq2, s, 0, 0, 0);
        s = __builtin_amdgcn_mfma_f32_32x32x16_bf16(k3, bq3, s, 0, 0, 0);

        // raw v_exp_f32 — inputs bounded (|S|log2e <= ~12)
        #pragma unroll
        for (int r = 0; r < 16; ++r) s[r] = EXP2(s[r]);
        l_loc += ((s[0] + s[1]) + (s[2] + s[3])) + ((s[4] + s[5]) + (s[6] + s[7])) +
                 ((s[8] + s[9]) + (s[10] + s[11])) + ((s[12] + s[13]) + (s[14] + s[15]));

        {   // keys 0..15
            unsigned int a0 = pk_bf16(s[0], s[1]);
            unsigned int a1 = pk_bf16(s[2], s[3]);
            unsigned int b0 = pk_bf16(s[4], s[5]);
            unsigned int b1 = pk_bf16(s[6], s[7]);
            uintx2 r0 = __builtin_amdgcn_permlane32_swap(a0, b0, false, false);
            uintx2 r1 = __builtin_amdgcn_permlane32_swap(a1, b1, false, false);
            uintx4 pwv = {r0[0], r1[0], r0[1], r1[1]};
            bf16x8 pa = __builtin_bit_cast(bf16x8, pwv);
            o0 = __builtin_amdgcn_mfma_f32_32x32x16_bf16(v00, pa, o0, 0, 0, 0);
            o1 = __builtin_amdgcn_mfma_f32_32x32x16_bf16(v10, pa, o1, 0, 0, 0);
        }
        {   // keys 16..31
            unsigned int a0 = pk_bf16(s[8], s[9]);
            unsigned int a1 = pk_bf16(s[10], s[11]);
            unsigned int b0 = pk_bf16(s[12], s[13]);
            unsigned int b1 = pk_bf16(s[14], s[15]);
            uintx2 r0 = __builtin_amdgcn_permlane32_swap(a0, b0, false, false);
            uintx2 r1 = __builtin_amdgcn_permlane32_swap(a1, b1, false, false);
            uintx4 pwv = {r0[0], r1[0], r0[1], r1[1]};
            bf16x8 pa = __builtin_bit_cast(bf16x8, pwv);
            o0 = __builtin_amdgcn_mfma_f32_32x32x16_bf16(v01, pa, o0, 0, 0, 0);
            o1 = __builtin_amdgcn_mfma_f32_32x32x16_bf16(v11, pa, o1, 0, 0, 0);
        }
    };

    // ---- K ping-pong: preload step 0 into set A ----
    bf16x8 kA0 = *(const bf16x8*)(kp + 0 * 512);
    bf16x8 kA1 = *(const bf16x8*)(kp + 1 * 512);
    bf16x8 kA2 = *(const bf16x8*)(kp + 2 * 512);
    bf16x8 kA3 = *(const bf16x8*)(kp + 3 * 512);

    for (int step = 0; step < 18; step += 2) {
        const unsigned short* kbB = kp + (size_t)(step + 1) * 2048;
        bf16x8 kB0 = *(const bf16x8*)(kbB + 0 * 512);
        bf16x8 kB1 = *(const bf16x8*)(kbB + 1 * 512);
        bf16x8 kB2 = *(const bf16x8*)(kbB + 2 * 512);
        bf16x8 kB3 = *(const bf16x8*)(kbB + 3 * 512);

        compute_step(kA0, kA1, kA2, kA3, step);

        int nx = (step + 2 < 18) ? (step + 2) : 0;
        const unsigned short* kbA = kp + (size_t)nx * 2048;
        kA0 = *(const bf16x8*)(kbA + 0 * 512);
        kA1 = *(const bf16x8*)(kbA + 1 * 512);
        kA2 = *(const bf16x8*)(kbA + 2 * 512);
        kA3 = *(const bf16x8*)(kbA + 3 * 512);

        compute_step(kB0, kB1, kB2, kB3, step + 1);
    }

    float l_full = l_loc + __shfl_xor(l_loc, 32);

    // ---- tree combine (fp32 exact): O = sum O_w / sum l_w ----
    if (w & 1) {
        float* sl = fl + (w >> 1) * 2112;
        #pragma unroll
        for (int reg = 0; reg < 16; ++reg) {
            sl[reg * 64 + lane] = o0[reg];
            sl[1024 + reg * 64 + lane] = o1[reg];
        }
        sl[2048 + lane] = l_full;
    }
    __syncthreads();
    if (!(w & 1)) {
        const float* sl = fl + (w >> 1) * 2112;
        #pragma unroll
        for (int reg = 0; reg < 16; ++reg) {
            o0[reg] += sl[reg * 64 + lane];
            o1[reg] += sl[1024 + reg * 64 + lane];
        }
        l_full += sl[2048 + lane];
    }
    __syncthreads();
    if (w == 2) {
        float* sl = fl;
        #pragma unroll
        for (int reg = 0; reg < 16; ++reg) {
            sl[reg * 64 + lane] = o0[reg];
            sl[1024 + reg * 64 + lane] = o1[reg];
        }
        sl[2048 + lane] = l_full;
    }
    __syncthreads();
    if (w != 0) return;

    #pragma unroll
    for (int reg = 0; reg < 16; ++reg) {
        o0[reg] += fl[reg * 64 + lane];
        o1[reg] += fl[1024 + reg * 64 + lane];
    }
    l_full += fl[2048 + lane];

    float inv = 1.f / l_full;
    o0 *= inv; o1 *= inv;

    // transpose O^T -> per-query rows (wave-0-local LDS reuse), write comb frags
    float* tw = fl;
    #pragma unroll
    for (int reg = 0; reg < 16; ++reg) {
        int rv = (reg & 3) + 8 * (reg >> 2) + 4 * h;
        tw[lq * 65 + rv] = o0[reg];
        tw[lq * 65 + 32 + rv] = o1[reg];
    }
    // chunk[lane*8+e] = comb[n=q0+(lane&31)][g = i*64 + ksl*16 + 8h + e]
    unsigned short* cb = wsb + OC + (size_t)j * CSTR +
                         ((size_t)((b * 72 + qp) * 12 + i * 4)) * 512;
    #pragma unroll
    for (int ksl = 0; ksl < 4; ++ksl) {
        const float* src = tw + lq * 65 + ksl * 16 + 8 * h;
        uintx4 pwv = {pk_bf16(src[0], src[1]), pk_bf16(src[2], src[3]),
                      pk_bf16(src[4], src[5]), pk_bf16(src[6], src[7])};
        *(uintx4*)(cb + ksl * 512 + lane * 8) = pwv;
    }
}

// ---------------------------------------------------------------------------
// Kernel: MFMA out-projection + sigmoid gate.
// ---------------------------------------------------------------------------
__global__ __launch_bounds__(256) void out_mfma(
    const float* __restrict__ x, const unsigned short* __restrict__ wsb,
    float* __restrict__ out)
{
    int bid = blockIdx.x;
    int ch = bid & 1;
    int nt = (bid >> 1) % 72;
    int b  = bid / 144;
    int n0 = nt * 32;
    int t = threadIdx.x;
    int w = t >> 6, lane = t & 63;
    int lq = lane & 31, h = lane >> 5;
    int rb = ch * 4 + w;

    const unsigned short* wof = wsb + OWOF + lane * 8;
    const unsigned short* cbase = wsb + OC +
        ((size_t)((b * 72 + nt) * 12)) * 512 + lane * 8;

    f32x16 acc = {};
    #pragma unroll
    for (int j = 0; j < 3; ++j) {
        const unsigned short* cj = cbase + (size_t)j * CSTR;
        #pragma unroll
        for (int ksx = 0; ksx < 12; ++ksx) {
            bf16x8 bx = *(const bf16x8*)(cj + ksx * 512);
            bf16x8 a0 = *(const bf16x8*)(wof + (ksx * 8 + rb) * 512);
            acc = __builtin_amdgcn_mfma_f32_32x32x16_bf16(a0, bx, acc, 0, 0, 0);
        }
    }

    int c0 = rb * 32;
    #pragma unroll
    for (int reg = 0; reg < 16; ++reg) {
        int c = c0 + (reg & 3) + 8 * (reg >> 2) + 4 * h;
        size_t idx = ((size_t)(b * CC + c)) * NN_ + n0 + lq;
        float sg = 1.f / (1.f + EXP2(acc[reg] * -1.44269504f));
        out[idx] = x[idx] * sg;
    }
}

extern "C" void kernel_launch(void* const* d_in, const int* in_sizes, int n_in,
                              void* d_out, int out_size, void* d_ws, size_t ws_size,
                              hipStream_t stream) {
    const float* x  = (const float*)d_in[0];
    const float* wq = (const float*)d_in[1];
    const float* wk = (const float*)d_in[2];
    const float* wv = (const float*)d_in[3];
    const float* wo = (const float*)d_in[4];
    unsigned short* wsb = (unsigned short*)d_ws;
    float* out = (float*)d_out;

    prep_kernel<<<300, 256, 0, stream>>>(x, wq, wk, wv, wo, wsb);
    proj_mfma<<<648, 256, 0, stream>>>(wsb);
    attn_kernel<<<2592, 256, 0, stream>>>(wsb);
    out_mfma<<<576, 256, 0, stream>>>(x, wsb, out);
}

// Round 19
// 92.736 us; speedup vs baseline: 1.0684x; 1.0366x over previous
//
#include <hip/hip_runtime.h>

// NestedAttention MI355X round 19: traffic-halving attn — wave owns 64
// queries (2 MFMA q-tiles) sharing ONE K/V stream: 16 MFMAs per 8KB loaded
// (was 8). L2 traffic 1.49GB -> 0.75GB. Block = 4 waves = one 64q group x
// 4 key-quarters; tree combine with doubled payload. launch_bounds(256,3).
//
// ws layout (ushort elems):
//   Qf  [3i][4b][72 t][4 f][512]     @ OQ
//   Kf  [3i][4b][72 t][4 f][512]     @ OK_
//   Vf  [3i][4b][72 t][2c][2rb][512] @ OV
//   combjf [3j][4b][72 nt][12 ks][512] @ OC (+j*CSTR)  (B-frag chunks)
//   xf  [4b][72 nb][16 ks][512]      @ OXF
//   Wf  [9 s][16 ks][2 rb][512]      @ OWF
//   WoF [12 ks][8 rb][512]           @ OWOF
// Frag chunk: chunk[lane*8+e] = Op[idx=lane&31][k=8*(lane>>5)+e]

#define BB 4
#define CC 256
#define NN_ 2304
#define RR 64

#define OQ 0
#define OK_ 1769472
#define OV 3538944
#define OC 5308416
#define CSTR 1769472
#define FR_IB 147456
#define OXF 10616832
#define OWF 12976128
#define OWOF 13123584

typedef __bf16 bf16x8 __attribute__((ext_vector_type(8)));
typedef float f32x16 __attribute__((ext_vector_type(16)));
typedef unsigned short ushort8 __attribute__((ext_vector_type(8)));
typedef unsigned int uintx2 __attribute__((ext_vector_type(2)));
typedef unsigned int uintx4 __attribute__((ext_vector_type(4)));

#if __has_builtin(__builtin_amdgcn_exp2f)
#define EXP2(x) __builtin_amdgcn_exp2f(x)
#else
#define EXP2(x) exp2f(x)
#endif

__device__ __forceinline__ float bf2f(unsigned short s) {
    unsigned int u = ((unsigned int)s) << 16;
    return __builtin_bit_cast(float, u);
}
__device__ __forceinline__ unsigned int pk_bf16(float lo, float hi) {
    unsigned int r;
    asm("v_cvt_pk_bf16_f32 %0, %1, %2" : "=v"(r) : "v"(lo), "v"(hi));
    return r;
}

// ---------------------------------------------------------------------------
// Prep: bid<9 weights->A-frags; bid<12 wo->A-frags; else x->B-frags.
// ---------------------------------------------------------------------------
__global__ __launch_bounds__(256) void prep_kernel(
    const float* __restrict__ x, const float* __restrict__ wq,
    const float* __restrict__ wk, const float* __restrict__ wv,
    const float* __restrict__ wo, unsigned short* __restrict__ wsb)
{
    int bid = blockIdx.x;
    int t = threadIdx.x;
    if (bid < 9) {
        int s = bid;
        int type = s / 3, i = s % 3;
        const float* wsel = (type == 0) ? wq : (type == 1 ? wk : wv);
        const float scale = (type == 0) ? 0.18033688011112042f : 1.0f;  // 0.125*log2e
        unsigned short* dst = wsb + OWF + s * 16384;
        #pragma unroll
        for (int p = 0; p < 8; ++p) {
            int u = t + 256 * p;
            int ks = u >> 7, rb = (u >> 6) & 1, lo = u & 63;
            int row = rb * 32 + (lo & 31), c = ks * 16 + 8 * (lo >> 5);
            const float* src = wsel + ((i * 64 + row) * 256 + c);
            float4 f0 = *(const float4*)(src);
            float4 f1 = *(const float4*)(src + 4);
            uintx4 pwv = {pk_bf16(f0.x * scale, f0.y * scale),
                          pk_bf16(f0.z * scale, f0.w * scale),
                          pk_bf16(f1.x * scale, f1.y * scale),
                          pk_bf16(f1.z * scale, f1.w * scale)};
            *(uintx4*)(dst + (ks * 2 + rb) * 512 + lo * 8) = pwv;
        }
        return;
    }
    if (bid < 12) {
        int bb = bid - 9;
        #pragma unroll
        for (int p = 0; p < 8; ++p) {
            int u = t + 256 * p;
            int cg = bb * 32 + (u >> 6);
            int lane = u & 63;
            int ks = cg >> 3, rb = cg & 7;
            int row = rb * 32 + (lane & 31);
            int g = ks * 16 + 8 * (lane >> 5);
            const float* src = wo + row * 192 + g;
            float4 f0 = *(const float4*)(src);
            float4 f1 = *(const float4*)(src + 4);
            uintx4 pwv = {pk_bf16(f0.x, f0.y), pk_bf16(f0.z, f0.w),
                          pk_bf16(f1.x, f1.y), pk_bf16(f1.z, f1.w)};
            *(uintx4*)(wsb + OWOF + cg * 512 + lane * 8) = pwv;
        }
        return;
    }
    __shared__ __align__(16) float xs[64 * 132];
    int xb = bid - 12;
    int cq  = xb & 3;
    int nt2 = (xb >> 2) % 18;
    int b   = xb / 72;
    int c0 = cq * 64, n0 = nt2 * 128;
    #pragma unroll
    for (int p = 0; p < 8; ++p) {
        int u = t + 256 * p;
        int cl = u >> 5, nq = (u & 31) * 4;
        *(float4*)&xs[cl * 132 + nq] =
            *(const float4*)&x[((size_t)(b * CC + c0 + cl)) * NN_ + n0 + nq];
    }
    __syncthreads();
    unsigned short* xfb = wsb + OXF + ((size_t)b) * 72 * 16 * 512;
    #pragma unroll
    for (int p = 0; p < 4; ++p) {
        int u = t + 256 * p;
        int nb_l = u >> 8, ks_l = (u >> 6) & 3, lo = u & 63;
        int hh = lo >> 5, idx = lo & 31;
        int clb = ks_l * 16 + 8 * hh;
        int nn = nb_l * 32 + idx;
        unsigned int pw[4];
        #pragma unroll
        for (int d = 0; d < 4; ++d) {
            float a  = xs[(clb + 2 * d) * 132 + nn];
            float bb2 = xs[(clb + 2 * d + 1) * 132 + nn];
            pw[d] = pk_bf16(a, bb2);
        }
        int nb = nt2 * 4 + nb_l, ks = cq * 4 + ks_l;
        *(uintx4*)(xfb + (nb * 16 + ks) * 512 + lo * 8) =
            (uintx4){pw[0], pw[1], pw[2], pw[3]};
    }
}

// ---------------------------------------------------------------------------
// Kernel: MFMA projection (unchanged structure).
// ---------------------------------------------------------------------------
__global__ __launch_bounds__(256) void proj_mfma(unsigned short* __restrict__ wsb)
{
    int bid = blockIdx.x;
    int s = bid / 72;
    int rem = bid % 72;
    int b = rem / 18, nb4 = rem % 18;
    int type = s / 3, i = s % 3;
    int t = threadIdx.x;
    int w = t >> 6, lane = t & 63;
    int lq = lane & 31, h = lane >> 5;
    int nb = nb4 * 4 + w;

    const unsigned short* wf = wsb + OWF + s * 16384 + lane * 8;
    const unsigned short* xf = wsb + OXF + ((size_t)(b * 72 + nb) * 16) * 512 + lane * 8;

    f32x16 o0 = {}, o1 = {};
    if (type < 2) {
        #pragma unroll
        for (int ks = 0; ks < 16; ++ks) {
            bf16x8 a0 = *(const bf16x8*)(wf + ks * 1024);
            bf16x8 a1 = *(const bf16x8*)(wf + ks * 1024 + 512);
            bf16x8 bx = *(const bf16x8*)(xf + ks * 512);
            o0 = __builtin_amdgcn_mfma_f32_32x32x16_bf16(a0, bx, o0, 0, 0, 0);
            o1 = __builtin_amdgcn_mfma_f32_32x32x16_bf16(a1, bx, o1, 0, 0, 0);
        }
    } else {
        #pragma unroll
        for (int ks = 0; ks < 16; ++ks) {
            bf16x8 a0 = *(const bf16x8*)(wf + ks * 1024);
            bf16x8 a1 = *(const bf16x8*)(wf + ks * 1024 + 512);
            bf16x8 bx = *(const bf16x8*)(xf + ks * 512);
            o0 = __builtin_amdgcn_mfma_f32_32x32x16_bf16(bx, a0, o0, 0, 0, 0);
            o1 = __builtin_amdgcn_mfma_f32_32x32x16_bf16(bx, a1, o1, 0, 0, 0);
        }
    }

    unsigned short* dstbase =
        wsb + ((type == 0) ? OQ : (type == 1 ? OK_ : OV)) +
        ((size_t)(i * 4 + b)) * FR_IB + nb * 2048;

    if (type < 2) {
        #pragma unroll
        for (int g = 0; g < 4; ++g) {
            int kd = 8 * g + 4 * h;
            int off = (kd >> 4) * 512 + ((kd >> 3) & 1) * 256 + lq * 8 + (kd & 7);
            *(uintx2*)(dstbase + off) =
                (uintx2){pk_bf16(o0[4 * g], o0[4 * g + 1]),
                         pk_bf16(o0[4 * g + 2], o0[4 * g + 3])};
            int kd2 = kd + 32;
            int off2 = (kd2 >> 4) * 512 + ((kd2 >> 3) & 1) * 256 + lq * 8 + (kd2 & 7);
            *(uintx2*)(dstbase + off2) =
                (uintx2){pk_bf16(o1[4 * g], o1[4 * g + 1]),
                         pk_bf16(o1[4 * g + 2], o1[4 * g + 3])};
        }
    } else {
        #pragma unroll
        for (int g = 0; g < 4; ++g) {
            int off = (g >> 1) * 1024 + (g & 1) * 256 + lq * 8 + 4 * h;
            *(uintx2*)(dstbase + off) =
                (uintx2){pk_bf16(o0[4 * g], o0[4 * g + 1]),
                         pk_bf16(o0[4 * g + 2], o0[4 * g + 3])};
            *(uintx2*)(dstbase + off + 512) =
                (uintx2){pk_bf16(o1[4 * g], o1[4 * g + 1]),
                         pk_bf16(o1[4 * g + 2], o1[4 * g + 3])};
        }
    }
}

// ---------------------------------------------------------------------------
// Kernel: barrier-free MFMA flash attention, 64 queries/wave (2 q-tiles
// sharing one K/V stream), 4-way key-split. Grid 1296 x 4 waves.
// ---------------------------------------------------------------------------
__global__ __launch_bounds__(256, 3) void attn_kernel(unsigned short* __restrict__ wsb)
{
    __shared__ __align__(16) float fl[8448];  // 2 slots x 4224 = 33.8KB

    int bid = blockIdx.x;
    int wid = (bid & 7) * 162 + (bid >> 3);   // XCD-bijective (1296 = 8*162)
    int s12 = wid / 108;                      // 12 (j,b) groups
    int rem = wid % 108;
    int j = s12 >> 2, b = s12 & 3;
    int i = rem / 36;
    int qg = rem % 36;                        // 64-query group
    int w = threadIdx.x >> 6;                 // key-quarter 0..3
    int lane = threadIdx.x & 63;
    int lq = lane & 31;
    int h = lane >> 5;

    const unsigned short* qbase = wsb + OQ + ((size_t)(i * 4 + b)) * FR_IB;
    const unsigned short* qtfA = qbase + (size_t)(qg * 2) * 2048 + lane * 8;
    const unsigned short* qtfB = qbase + (size_t)(qg * 2 + 1) * 2048 + lane * 8;
    const unsigned short* kp = wsb + OK_ + ((size_t)(j * 4 + b)) * FR_IB +
                               (size_t)(w * 18) * 2048 + lane * 8;
    const unsigned short* vp = wsb + OV + ((size_t)(j * 4 + b)) * FR_IB +
                               (size_t)(w * 18) * 2048 + lane * 8;

    bf16x8 bqA0 = *(const bf16x8*)(qtfA + 0);
    bf16x8 bqA1 = *(const bf16x8*)(qtfA + 512);
    bf16x8 bqA2 = *(const bf16x8*)(qtfA + 1024);
    bf16x8 bqA3 = *(const bf16x8*)(qtfA + 1536);
    bf16x8 bqB0 = *(const bf16x8*)(qtfB + 0);
    bf16x8 bqB1 = *(const bf16x8*)(qtfB + 512);
    bf16x8 bqB2 = *(const bf16x8*)(qtfB + 1024);
    bf16x8 bqB3 = *(const bf16x8*)(qtfB + 1536);

    f32x16 o0a = {}, o1a = {}, o0b = {}, o1b = {};
    float la = 0.f, lb = 0.f;

    // finish: exp, l, pack, PV into the given accumulators (V shared)
    auto finish = [&](f32x16& s, f32x16& oo0, f32x16& oo1, float& ll,
                      bf16x8 v00, bf16x8 v10, bf16x8 v01, bf16x8 v11) {
        #pragma unroll
        for (int r = 0; r < 16; ++r) s[r] = EXP2(s[r]);
        ll += ((s[0] + s[1]) + (s[2] + s[3])) + ((s[4] + s[5]) + (s[6] + s[7])) +
              ((s[8] + s[9]) + (s[10] + s[11])) + ((s[12] + s[13]) + (s[14] + s[15]));
        {   // keys 0..15
            unsigned int a0 = pk_bf16(s[0], s[1]);
            unsigned int a1 = pk_bf16(s[2], s[3]);
            unsigned int b0 = pk_bf16(s[4], s[5]);
            unsigned int b1 = pk_bf16(s[6], s[7]);
            uintx2 r0 = __builtin_amdgcn_permlane32_swap(a0, b0, false, false);
            uintx2 r1 = __builtin_amdgcn_permlane32_swap(a1, b1, false, false);
            uintx4 pwv = {r0[0], r1[0], r0[1], r1[1]};
            bf16x8 pa = __builtin_bit_cast(bf16x8, pwv);
            oo0 = __builtin_amdgcn_mfma_f32_32x32x16_bf16(v00, pa, oo0, 0, 0, 0);
            oo1 = __builtin_amdgcn_mfma_f32_32x32x16_bf16(v10, pa, oo1, 0, 0, 0);
        }
        {   // keys 16..31
            unsigned int a0 = pk_bf16(s[8], s[9]);
            unsigned int a1 = pk_bf16(s[10], s[11]);
            unsigned int b0 = pk_bf16(s[12], s[13]);
            unsigned int b1 = pk_bf16(s[14], s[15]);
            uintx2 r0 = __builtin_amdgcn_permlane32_swap(a0, b0, false, false);
            uintx2 r1 = __builtin_amdgcn_permlane32_swap(a1, b1, false, false);
            uintx4 pwv = {r0[0], r1[0], r0[1], r1[1]};
            bf16x8 pa = __builtin_bit_cast(bf16x8, pwv);
            oo0 = __builtin_amdgcn_mfma_f32_32x32x16_bf16(v01, pa, oo0, 0, 0, 0);
            oo1 = __builtin_amdgcn_mfma_f32_32x32x16_bf16(v11, pa, oo1, 0, 0, 0);
        }
    };

    // preload K for step 0
    bf16x8 k0 = *(const bf16x8*)(kp + 0 * 512);
    bf16x8 k1 = *(const bf16x8*)(kp + 1 * 512);
    bf16x8 k2 = *(const bf16x8*)(kp + 2 * 512);
    bf16x8 k3 = *(const bf16x8*)(kp + 3 * 512);

    for (int step = 0; step < 18; ++step) {
        const unsigned short* vb = vp + (size_t)step * 2048;
        bf16x8 v00 = *(const bf16x8*)(vb + 0 * 512);  // c0,rb0
        bf16x8 v10 = *(const bf16x8*)(vb + 1 * 512);  // c0,rb1
        bf16x8 v01 = *(const bf16x8*)(vb + 2 * 512);  // c1,rb0
        bf16x8 v11 = *(const bf16x8*)(vb + 3 * 512);  // c1,rb1

        // tile A scores
        f32x16 s = {};
        s = __builtin_amdgcn_mfma_f32_32x32x16_bf16(k0, bqA0, s, 0, 0, 0);
        s = __builtin_amdgcn_mfma_f32_32x32x16_bf16(k1, bqA1, s, 0, 0, 0);
        s = __builtin_amdgcn_mfma_f32_32x32x16_bf16(k2, bqA2, s, 0, 0, 0);
        s = __builtin_amdgcn_mfma_f32_32x32x16_bf16(k3, bqA3, s, 0, 0, 0);
        finish(s, o0a, o1a, la, v00, v10, v01, v11);

        // tile B scores (same K)
        f32x16 s2 = {};
        s2 = __builtin_amdgcn_mfma_f32_32x32x16_bf16(k0, bqB0, s2, 0, 0, 0);
        s2 = __builtin_amdgcn_mfma_f32_32x32x16_bf16(k1, bqB1, s2, 0, 0, 0);
        s2 = __builtin_amdgcn_mfma_f32_32x32x16_bf16(k2, bqB2, s2, 0, 0, 0);
        s2 = __builtin_amdgcn_mfma_f32_32x32x16_bf16(k3, bqB3, s2, 0, 0, 0);
        {   // K dead after tile-B QK -> reload for step+1
            int nx = (step + 1 < 18) ? (step + 1) : 0;
            const unsigned short* kb = kp + (size_t)nx * 2048;
            k0 = *(const bf16x8*)(kb + 0 * 512);
            k1 = *(const bf16x8*)(kb + 1 * 512);
            k2 = *(const bf16x8*)(kb + 2 * 512);
            k3 = *(const bf16x8*)(kb + 3 * 512);
        }
        finish(s2, o0b, o1b, lb, v00, v10, v01, v11);
    }

    float la_f = la + __shfl_xor(la, 32);
    float lb_f = lb + __shfl_xor(lb, 32);

    // ---- tree combine over 4 key-quarters (fp32 exact) ----
    if (w & 1) {
        float* sl = fl + (w >> 1) * 4224;
        #pragma unroll
        for (int reg = 0; reg < 16; ++reg) {
            sl[reg * 64 + lane] = o0a[reg];
            sl[1024 + reg * 64 + lane] = o1a[reg];
            sl[2048 + reg * 64 + lane] = o0b[reg];
            sl[3072 + reg * 64 + lane] = o1b[reg];
        }
        sl[4096 + lane] = la_f;
        sl[4160 + lane] = lb_f;
    }
    __syncthreads();
    if (!(w & 1)) {
        const float* sl = fl + (w >> 1) * 4224;
        #pragma unroll
        for (int reg = 0; reg < 16; ++reg) {
            o0a[reg] += sl[reg * 64 + lane];
            o1a[reg] += sl[1024 + reg * 64 + lane];
            o0b[reg] += sl[2048 + reg * 64 + lane];
            o1b[reg] += sl[3072 + reg * 64 + lane];
        }
        la_f += sl[4096 + lane];
        lb_f += sl[4160 + lane];
    }
    __syncthreads();
    if (w == 2) {
        float* sl = fl;
        #pragma unroll
        for (int reg = 0; reg < 16; ++reg) {
            sl[reg * 64 + lane] = o0a[reg];
            sl[1024 + reg * 64 + lane] = o1a[reg];
            sl[2048 + reg * 64 + lane] = o0b[reg];
            sl[3072 + reg * 64 + lane] = o1b[reg];
        }
        sl[4096 + lane] = la_f;
        sl[4160 + lane] = lb_f;
    }
    __syncthreads();
    if (w != 0) return;

    #pragma unroll
    for (int reg = 0; reg < 16; ++reg) {
        o0a[reg] += fl[reg * 64 + lane];
        o1a[reg] += fl[1024 + reg * 64 + lane];
        o0b[reg] += fl[2048 + reg * 64 + lane];
        o1b[reg] += fl[3072 + reg * 64 + lane];
    }
    la_f += fl[4096 + lane];
    lb_f += fl[4160 + lane];

    float inva = 1.f / la_f, invb = 1.f / lb_f;
    o0a *= inva; o1a *= inva;
    o0b *= invb; o1b *= invb;

    // write both q-tiles (wave 0 alone; same-wave LDS reuse is in-order)
    auto emit = [&](f32x16 oo0, f32x16 oo1, int qp) {
        float* tw = fl;
        #pragma unroll
        for (int reg = 0; reg < 16; ++reg) {
            int rv = (reg & 3) + 8 * (reg >> 2) + 4 * h;
            tw[lq * 65 + rv] = oo0[reg];
            tw[lq * 65 + 32 + rv] = oo1[reg];
        }
        unsigned short* cb = wsb + OC + (size_t)j * CSTR +
                             ((size_t)((b * 72 + qp) * 12 + i * 4)) * 512;
        #pragma unroll
        for (int ksl = 0; ksl < 4; ++ksl) {
            const float* src = tw + lq * 65 + ksl * 16 + 8 * h;
            uintx4 pwv = {pk_bf16(src[0], src[1]), pk_bf16(src[2], src[3]),
                          pk_bf16(src[4], src[5]), pk_bf16(src[6], src[7])};
            *(uintx4*)(cb + ksl * 512 + lane * 8) = pwv;
        }
    };
    emit(o0a, o1a, qg * 2);
    emit(o0b, o1b, qg * 2 + 1);
}

// ---------------------------------------------------------------------------
// Kernel: MFMA out-projection + sigmoid gate.
// ---------------------------------------------------------------------------
__global__ __launch_bounds__(256) void out_mfma(
    const float* __restrict__ x, const unsigned short* __restrict__ wsb,
    float* __restrict__ out)
{
    int bid = blockIdx.x;
    int ch = bid & 1;
    int nt = (bid >> 1) % 72;
    int b  = bid / 144;
    int n0 = nt * 32;
    int t = threadIdx.x;
    int w = t >> 6, lane = t & 63;
    int lq = lane & 31, h = lane >> 5;
    int rb = ch * 4 + w;

    const unsigned short* wof = wsb + OWOF + lane * 8;
    const unsigned short* cbase = wsb + OC +
        ((size_t)((b * 72 + nt) * 12)) * 512 + lane * 8;

    f32x16 acc = {};
    #pragma unroll
    for (int j = 0; j < 3; ++j) {
        const unsigned short* cj = cbase + (size_t)j * CSTR;
        #pragma unroll
        for (int ksx = 0; ksx < 12; ++ksx) {
            bf16x8 bx = *(const bf16x8*)(cj + ksx * 512);
            bf16x8 a0 = *(const bf16x8*)(wof + (ksx * 8 + rb) * 512);
            acc = __builtin_amdgcn_mfma_f32_32x32x16_bf16(a0, bx, acc, 0, 0, 0);
        }
    }

    int c0 = rb * 32;
    #pragma unroll
    for (int reg = 0; reg < 16; ++reg) {
        int c = c0 + (reg & 3) + 8 * (reg >> 2) + 4 * h;
        size_t idx = ((size_t)(b * CC + c)) * NN_ + n0 + lq;
        float sg = 1.f / (1.f + EXP2(acc[reg] * -1.44269504f));
        out[idx] = x[idx] * sg;
    }
}

extern "C" void kernel_launch(void* const* d_in, const int* in_sizes, int n_in,
                              void* d_out, int out_size, void* d_ws, size_t ws_size,
                              hipStream_t stream) {
    const float* x  = (const float*)d_in[0];
    const float* wq = (const float*)d_in[1];
    const float* wk = (const float*)d_in[2];
    const float* wv = (const float*)d_in[3];
    const float* wo = (const float*)d_in[4];
    unsigned short* wsb = (unsigned short*)d_ws;
    float* out = (float*)d_out;

    prep_kernel<<<300, 256, 0, stream>>>(x, wq, wk, wv, wo, wsb);
    proj_mfma<<<648, 256, 0, stream>>>(wsb);
    attn_kernel<<<1296, 256, 0, stream>>>(wsb);
    out_mfma<<<576, 256, 0, stream>>>(x, wsb, out);
}

// Round 20
// 92.334 us; speedup vs baseline: 1.0731x; 1.0044x over previous
//
#include <hip/hip_runtime.h>

// NestedAttention MI355X round 20: micro-VALU trim on the round-19 winner —
// (1) hoisted zero C-operand for QK MFMAs (kills 576 v_mov/wave of s={} init),
// (2) V loads issued after tile-A QK (shorter V liveness, relaxes the frame).
// Structure otherwise = round 19 (64q/wave, 4-way key-split, tree combine).
//
// ws layout (ushort elems):
//   Qf  [3i][4b][72 t][4 f][512]     @ OQ
//   Kf  [3i][4b][72 t][4 f][512]     @ OK_
//   Vf  [3i][4b][72 t][2c][2rb][512] @ OV
//   combjf [3j][4b][72 nt][12 ks][512] @ OC (+j*CSTR)  (B-frag chunks)
//   xf  [4b][72 nb][16 ks][512]      @ OXF
//   Wf  [9 s][16 ks][2 rb][512]      @ OWF
//   WoF [12 ks][8 rb][512]           @ OWOF
// Frag chunk: chunk[lane*8+e] = Op[idx=lane&31][k=8*(lane>>5)+e]

#define BB 4
#define CC 256
#define NN_ 2304
#define RR 64

#define OQ 0
#define OK_ 1769472
#define OV 3538944
#define OC 5308416
#define CSTR 1769472
#define FR_IB 147456
#define OXF 10616832
#define OWF 12976128
#define OWOF 13123584

typedef __bf16 bf16x8 __attribute__((ext_vector_type(8)));
typedef float f32x16 __attribute__((ext_vector_type(16)));
typedef unsigned short ushort8 __attribute__((ext_vector_type(8)));
typedef unsigned int uintx2 __attribute__((ext_vector_type(2)));
typedef unsigned int uintx4 __attribute__((ext_vector_type(4)));

#if __has_builtin(__builtin_amdgcn_exp2f)
#define EXP2(x) __builtin_amdgcn_exp2f(x)
#else
#define EXP2(x) exp2f(x)
#endif

__device__ __forceinline__ float bf2f(unsigned short s) {
    unsigned int u = ((unsigned int)s) << 16;
    return __builtin_bit_cast(float, u);
}
__device__ __forceinline__ unsigned int pk_bf16(float lo, float hi) {
    unsigned int r;
    asm("v_cvt_pk_bf16_f32 %0, %1, %2" : "=v"(r) : "v"(lo), "v"(hi));
    return r;
}

// ---------------------------------------------------------------------------
// Prep: bid<9 weights->A-frags; bid<12 wo->A-frags; else x->B-frags.
// ---------------------------------------------------------------------------
__global__ __launch_bounds__(256) void prep_kernel(
    const float* __restrict__ x, const float* __restrict__ wq,
    const float* __restrict__ wk, const float* __restrict__ wv,
    const float* __restrict__ wo, unsigned short* __restrict__ wsb)
{
    int bid = blockIdx.x;
    int t = threadIdx.x;
    if (bid < 9) {
        int s = bid;
        int type = s / 3, i = s % 3;
        const float* wsel = (type == 0) ? wq : (type == 1 ? wk : wv);
        const float scale = (type == 0) ? 0.18033688011112042f : 1.0f;  // 0.125*log2e
        unsigned short* dst = wsb + OWF + s * 16384;
        #pragma unroll
        for (int p = 0; p < 8; ++p) {
            int u = t + 256 * p;
            int ks = u >> 7, rb = (u >> 6) & 1, lo = u & 63;
            int row = rb * 32 + (lo & 31), c = ks * 16 + 8 * (lo >> 5);
            const float* src = wsel + ((i * 64 + row) * 256 + c);
            float4 f0 = *(const float4*)(src);
            float4 f1 = *(const float4*)(src + 4);
            uintx4 pwv = {pk_bf16(f0.x * scale, f0.y * scale),
                          pk_bf16(f0.z * scale, f0.w * scale),
                          pk_bf16(f1.x * scale, f1.y * scale),
                          pk_bf16(f1.z * scale, f1.w * scale)};
            *(uintx4*)(dst + (ks * 2 + rb) * 512 + lo * 8) = pwv;
        }
        return;
    }
    if (bid < 12) {
        int bb = bid - 9;
        #pragma unroll
        for (int p = 0; p < 8; ++p) {
            int u = t + 256 * p;
            int cg = bb * 32 + (u >> 6);
            int lane = u & 63;
            int ks = cg >> 3, rb = cg & 7;
            int row = rb * 32 + (lane & 31);
            int g = ks * 16 + 8 * (lane >> 5);
            const float* src = wo + row * 192 + g;
            float4 f0 = *(const float4*)(src);
            float4 f1 = *(const float4*)(src + 4);
            uintx4 pwv = {pk_bf16(f0.x, f0.y), pk_bf16(f0.z, f0.w),
                          pk_bf16(f1.x, f1.y), pk_bf16(f1.z, f1.w)};
            *(uintx4*)(wsb + OWOF + cg * 512 + lane * 8) = pwv;
        }
        return;
    }
    __shared__ __align__(16) float xs[64 * 132];
    int xb = bid - 12;
    int cq  = xb & 3;
    int nt2 = (xb >> 2) % 18;
    int b   = xb / 72;
    int c0 = cq * 64, n0 = nt2 * 128;
    #pragma unroll
    for (int p = 0; p < 8; ++p) {
        int u = t + 256 * p;
        int cl = u >> 5, nq = (u & 31) * 4;
        *(float4*)&xs[cl * 132 + nq] =
            *(const float4*)&x[((size_t)(b * CC + c0 + cl)) * NN_ + n0 + nq];
    }
    __syncthreads();
    unsigned short* xfb = wsb + OXF + ((size_t)b) * 72 * 16 * 512;
    #pragma unroll
    for (int p = 0; p < 4; ++p) {
        int u = t + 256 * p;
        int nb_l = u >> 8, ks_l = (u >> 6) & 3, lo = u & 63;
        int hh = lo >> 5, idx = lo & 31;
        int clb = ks_l * 16 + 8 * hh;
        int nn = nb_l * 32 + idx;
        unsigned int pw[4];
        #pragma unroll
        for (int d = 0; d < 4; ++d) {
            float a  = xs[(clb + 2 * d) * 132 + nn];
            float bb2 = xs[(clb + 2 * d + 1) * 132 + nn];
            pw[d] = pk_bf16(a, bb2);
        }
        int nb = nt2 * 4 + nb_l, ks = cq * 4 + ks_l;
        *(uintx4*)(xfb + (nb * 16 + ks) * 512 + lo * 8) =
            (uintx4){pw[0], pw[1], pw[2], pw[3]};
    }
}

// ---------------------------------------------------------------------------
// Kernel: MFMA projection (unchanged structure).
// ---------------------------------------------------------------------------
__global__ __launch_bounds__(256) void proj_mfma(unsigned short* __restrict__ wsb)
{
    int bid = blockIdx.x;
    int s = bid / 72;
    int rem = bid % 72;
    int b = rem / 18, nb4 = rem % 18;
    int type = s / 3, i = s % 3;
    int t = threadIdx.x;
    int w = t >> 6, lane = t & 63;
    int lq = lane & 31, h = lane >> 5;
    int nb = nb4 * 4 + w;

    const unsigned short* wf = wsb + OWF + s * 16384 + lane * 8;
    const unsigned short* xf = wsb + OXF + ((size_t)(b * 72 + nb) * 16) * 512 + lane * 8;

    f32x16 o0 = {}, o1 = {};
    if (type < 2) {
        #pragma unroll
        for (int ks = 0; ks < 16; ++ks) {
            bf16x8 a0 = *(const bf16x8*)(wf + ks * 1024);
            bf16x8 a1 = *(const bf16x8*)(wf + ks * 1024 + 512);
            bf16x8 bx = *(const bf16x8*)(xf + ks * 512);
            o0 = __builtin_amdgcn_mfma_f32_32x32x16_bf16(a0, bx, o0, 0, 0, 0);
            o1 = __builtin_amdgcn_mfma_f32_32x32x16_bf16(a1, bx, o1, 0, 0, 0);
        }
    } else {
        #pragma unroll
        for (int ks = 0; ks < 16; ++ks) {
            bf16x8 a0 = *(const bf16x8*)(wf + ks * 1024);
            bf16x8 a1 = *(const bf16x8*)(wf + ks * 1024 + 512);
            bf16x8 bx = *(const bf16x8*)(xf + ks * 512);
            o0 = __builtin_amdgcn_mfma_f32_32x32x16_bf16(bx, a0, o0, 0, 0, 0);
            o1 = __builtin_amdgcn_mfma_f32_32x32x16_bf16(bx, a1, o1, 0, 0, 0);
        }
    }

    unsigned short* dstbase =
        wsb + ((type == 0) ? OQ : (type == 1 ? OK_ : OV)) +
        ((size_t)(i * 4 + b)) * FR_IB + nb * 2048;

    if (type < 2) {
        #pragma unroll
        for (int g = 0; g < 4; ++g) {
            int kd = 8 * g + 4 * h;
            int off = (kd >> 4) * 512 + ((kd >> 3) & 1) * 256 + lq * 8 + (kd & 7);
            *(uintx2*)(dstbase + off) =
                (uintx2){pk_bf16(o0[4 * g], o0[4 * g + 1]),
                         pk_bf16(o0[4 * g + 2], o0[4 * g + 3])};
            int kd2 = kd + 32;
            int off2 = (kd2 >> 4) * 512 + ((kd2 >> 3) & 1) * 256 + lq * 8 + (kd2 & 7);
            *(uintx2*)(dstbase + off2) =
                (uintx2){pk_bf16(o1[4 * g], o1[4 * g + 1]),
                         pk_bf16(o1[4 * g + 2], o1[4 * g + 3])};
        }
    } else {
        #pragma unroll
        for (int g = 0; g < 4; ++g) {
            int off = (g >> 1) * 1024 + (g & 1) * 256 + lq * 8 + 4 * h;
            *(uintx2*)(dstbase + off) =
                (uintx2){pk_bf16(o0[4 * g], o0[4 * g + 1]),
                         pk_bf16(o0[4 * g + 2], o0[4 * g + 3])};
            *(uintx2*)(dstbase + off + 512) =
                (uintx2){pk_bf16(o1[4 * g], o1[4 * g + 1]),
                         pk_bf16(o1[4 * g + 2], o1[4 * g + 3])};
        }
    }
}

// ---------------------------------------------------------------------------
// Kernel: barrier-free MFMA flash attention, 64 queries/wave (2 q-tiles
// sharing one K/V stream), 4-way key-split. Hoisted zero C-operand.
// ---------------------------------------------------------------------------
__global__ __launch_bounds__(256, 3) void attn_kernel(unsigned short* __restrict__ wsb)
{
    __shared__ __align__(16) float fl[8448];  // 2 slots x 4224 = 33.8KB

    int bid = blockIdx.x;
    int wid = (bid & 7) * 162 + (bid >> 3);   // XCD-bijective (1296 = 8*162)
    int s12 = wid / 108;                      // 12 (j,b) groups
    int rem = wid % 108;
    int j = s12 >> 2, b = s12 & 3;
    int i = rem / 36;
    int qg = rem % 36;                        // 64-query group
    int w = threadIdx.x >> 6;                 // key-quarter 0..3
    int lane = threadIdx.x & 63;
    int lq = lane & 31;
    int h = lane >> 5;

    const unsigned short* qbase = wsb + OQ + ((size_t)(i * 4 + b)) * FR_IB;
    const unsigned short* qtfA = qbase + (size_t)(qg * 2) * 2048 + lane * 8;
    const unsigned short* qtfB = qbase + (size_t)(qg * 2 + 1) * 2048 + lane * 8;
    const unsigned short* kp = wsb + OK_ + ((size_t)(j * 4 + b)) * FR_IB +
                               (size_t)(w * 18) * 2048 + lane * 8;
    const unsigned short* vp = wsb + OV + ((size_t)(j * 4 + b)) * FR_IB +
                               (size_t)(w * 18) * 2048 + lane * 8;

    bf16x8 bqA0 = *(const bf16x8*)(qtfA + 0);
    bf16x8 bqA1 = *(const bf16x8*)(qtfA + 512);
    bf16x8 bqA2 = *(const bf16x8*)(qtfA + 1024);
    bf16x8 bqA3 = *(const bf16x8*)(qtfA + 1536);
    bf16x8 bqB0 = *(const bf16x8*)(qtfB + 0);
    bf16x8 bqB1 = *(const bf16x8*)(qtfB + 512);
    bf16x8 bqB2 = *(const bf16x8*)(qtfB + 1024);
    bf16x8 bqB3 = *(const bf16x8*)(qtfB + 1536);

    f32x16 o0a = {}, o1a = {}, o0b = {}, o1b = {};
    float la = 0.f, lb = 0.f;
    const f32x16 zeroc = {};   // hoisted C-operand: no per-iter s={} movs

    // finish: exp, l, pack, PV into the given accumulators (V shared)
    auto finish = [&](f32x16& s, f32x16& oo0, f32x16& oo1, float& ll,
                      bf16x8 v00, bf16x8 v10, bf16x8 v01, bf16x8 v11) {
        #pragma unroll
        for (int r = 0; r < 16; ++r) s[r] = EXP2(s[r]);
        ll += ((s[0] + s[1]) + (s[2] + s[3])) + ((s[4] + s[5]) + (s[6] + s[7])) +
              ((s[8] + s[9]) + (s[10] + s[11])) + ((s[12] + s[13]) + (s[14] + s[15]));
        {   // keys 0..15
            unsigned int a0 = pk_bf16(s[0], s[1]);
            unsigned int a1 = pk_bf16(s[2], s[3]);
            unsigned int b0 = pk_bf16(s[4], s[5]);
            unsigned int b1 = pk_bf16(s[6], s[7]);
            uintx2 r0 = __builtin_amdgcn_permlane32_swap(a0, b0, false, false);
            uintx2 r1 = __builtin_amdgcn_permlane32_swap(a1, b1, false, false);
            uintx4 pwv = {r0[0], r1[0], r0[1], r1[1]};
            bf16x8 pa = __builtin_bit_cast(bf16x8, pwv);
            oo0 = __builtin_amdgcn_mfma_f32_32x32x16_bf16(v00, pa, oo0, 0, 0, 0);
            oo1 = __builtin_amdgcn_mfma_f32_32x32x16_bf16(v10, pa, oo1, 0, 0, 0);
        }
        {   // keys 16..31
            unsigned int a0 = pk_bf16(s[8], s[9]);
            unsigned int a1 = pk_bf16(s[10], s[11]);
            unsigned int b0 = pk_bf16(s[12], s[13]);
            unsigned int b1 = pk_bf16(s[14], s[15]);
            uintx2 r0 = __builtin_amdgcn_permlane32_swap(a0, b0, false, false);
            uintx2 r1 = __builtin_amdgcn_permlane32_swap(a1, b1, false, false);
            uintx4 pwv = {r0[0], r1[0], r0[1], r1[1]};
            bf16x8 pa = __builtin_bit_cast(bf16x8, pwv);
            oo0 = __builtin_amdgcn_mfma_f32_32x32x16_bf16(v01, pa, oo0, 0, 0, 0);
            oo1 = __builtin_amdgcn_mfma_f32_32x32x16_bf16(v11, pa, oo1, 0, 0, 0);
        }
    };

    // preload K for step 0
    bf16x8 k0 = *(const bf16x8*)(kp + 0 * 512);
    bf16x8 k1 = *(const bf16x8*)(kp + 1 * 512);
    bf16x8 k2 = *(const bf16x8*)(kp + 2 * 512);
    bf16x8 k3 = *(const bf16x8*)(kp + 3 * 512);

    for (int step = 0; step < 18; ++step) {
        // tile A scores (hoisted zero C)
        f32x16 s = __builtin_amdgcn_mfma_f32_32x32x16_bf16(k0, bqA0, zeroc, 0, 0, 0);
        s = __builtin_amdgcn_mfma_f32_32x32x16_bf16(k1, bqA1, s, 0, 0, 0);
        s = __builtin_amdgcn_mfma_f32_32x32x16_bf16(k2, bqA2, s, 0, 0, 0);
        s = __builtin_amdgcn_mfma_f32_32x32x16_bf16(k3, bqA3, s, 0, 0, 0);

        // V loads issued after tile-A QK (land under exp/pack; short liveness)
        const unsigned short* vb = vp + (size_t)step * 2048;
        bf16x8 v00 = *(const bf16x8*)(vb + 0 * 512);  // c0,rb0
        bf16x8 v10 = *(const bf16x8*)(vb + 1 * 512);  // c0,rb1
        bf16x8 v01 = *(const bf16x8*)(vb + 2 * 512);  // c1,rb0
        bf16x8 v11 = *(const bf16x8*)(vb + 3 * 512);  // c1,rb1

        finish(s, o0a, o1a, la, v00, v10, v01, v11);

        // tile B scores (same K)
        f32x16 s2 = __builtin_amdgcn_mfma_f32_32x32x16_bf16(k0, bqB0, zeroc, 0, 0, 0);
        s2 = __builtin_amdgcn_mfma_f32_32x32x16_bf16(k1, bqB1, s2, 0, 0, 0);
        s2 = __builtin_amdgcn_mfma_f32_32x32x16_bf16(k2, bqB2, s2, 0, 0, 0);
        s2 = __builtin_amdgcn_mfma_f32_32x32x16_bf16(k3, bqB3, s2, 0, 0, 0);
        {   // K dead after tile-B QK -> reload for step+1 (wrap last)
            int nx = (step + 1 < 18) ? (step + 1) : 0;
            const unsigned short* kb = kp + (size_t)nx * 2048;
            k0 = *(const bf16x8*)(kb + 0 * 512);
            k1 = *(const bf16x8*)(kb + 1 * 512);
            k2 = *(const bf16x8*)(kb + 2 * 512);
            k3 = *(const bf16x8*)(kb + 3 * 512);
        }
        finish(s2, o0b, o1b, lb, v00, v10, v01, v11);
    }

    float la_f = la + __shfl_xor(la, 32);
    float lb_f = lb + __shfl_xor(lb, 32);

    // ---- tree combine over 4 key-quarters (fp32 exact) ----
    if (w & 1) {
        float* sl = fl + (w >> 1) * 4224;
        #pragma unroll
        for (int reg = 0; reg < 16; ++reg) {
            sl[reg * 64 + lane] = o0a[reg];
            sl[1024 + reg * 64 + lane] = o1a[reg];
            sl[2048 + reg * 64 + lane] = o0b[reg];
            sl[3072 + reg * 64 + lane] = o1b[reg];
        }
        sl[4096 + lane] = la_f;
        sl[4160 + lane] = lb_f;
    }
    __syncthreads();
    if (!(w & 1)) {
        const float* sl = fl + (w >> 1) * 4224;
        #pragma unroll
        for (int reg = 0; reg < 16; ++reg) {
            o0a[reg] += sl[reg * 64 + lane];
            o1a[reg] += sl[1024 + reg * 64 + lane];
            o0b[reg] += sl[2048 + reg * 64 + lane];
            o1b[reg] += sl[3072 + reg * 64 + lane];
        }
        la_f += sl[4096 + lane];
        lb_f += sl[4160 + lane];
    }
    __syncthreads();
    if (w == 2) {
        float* sl = fl;
        #pragma unroll
        for (int reg = 0; reg < 16; ++reg) {
            sl[reg * 64 + lane] = o0a[reg];
            sl[1024 + reg * 64 + lane] = o1a[reg];
            sl[2048 + reg * 64 + lane] = o0b[reg];
            sl[3072 + reg * 64 + lane] = o1b[reg];
        }
        sl[4096 + lane] = la_f;
        sl[4160 + lane] = lb_f;
    }
    __syncthreads();
    if (w != 0) return;

    #pragma unroll
    for (int reg = 0; reg < 16; ++reg) {
        o0a[reg] += fl[reg * 64 + lane];
        o1a[reg] += fl[1024 + reg * 64 + lane];
        o0b[reg] += fl[2048 + reg * 64 + lane];
        o1b[reg] += fl[3072 + reg * 64 + lane];
    }
    la_f += fl[4096 + lane];
    lb_f += fl[4160 + lane];

    float inva = 1.f / la_f, invb = 1.f / lb_f;
    o0a *= inva; o1a *= inva;
    o0b *= invb; o1b *= invb;

    // write both q-tiles (wave 0 alone; same-wave LDS reuse is in-order)
    auto emit = [&](f32x16 oo0, f32x16 oo1, int qp) {
        float* tw = fl;
        #pragma unroll
        for (int reg = 0; reg < 16; ++reg) {
            int rv = (reg & 3) + 8 * (reg >> 2) + 4 * h;
            tw[lq * 65 + rv] = oo0[reg];
            tw[lq * 65 + 32 + rv] = oo1[reg];
        }
        unsigned short* cb = wsb + OC + (size_t)j * CSTR +
                             ((size_t)((b * 72 + qp) * 12 + i * 4)) * 512;
        #pragma unroll
        for (int ksl = 0; ksl < 4; ++ksl) {
            const float* src = tw + lq * 65 + ksl * 16 + 8 * h;
            uintx4 pwv = {pk_bf16(src[0], src[1]), pk_bf16(src[2], src[3]),
                          pk_bf16(src[4], src[5]), pk_bf16(src[6], src[7])};
            *(uintx4*)(cb + ksl * 512 + lane * 8) = pwv;
        }
    };
    emit(o0a, o1a, qg * 2);
    emit(o0b, o1b, qg * 2 + 1);
}

// ---------------------------------------------------------------------------
// Kernel: MFMA out-projection + sigmoid gate.
// ---------------------------------------------------------------------------
__global__ __launch_bounds__(256) void out_mfma(
    const float* __restrict__ x, const unsigned short* __restrict__ wsb,
    float* __restrict__ out)
{
    int bid = blockIdx.x;
    int ch = bid & 1;
    int nt = (bid >> 1) % 72;
    int b  = bid / 144;
    int n0 = nt * 32;
    int t = threadIdx.x;
    int w = t >> 6, lane = t & 63;
    int lq = lane & 31, h = lane >> 5;
    int rb = ch * 4 + w;

    const unsigned short* wof = wsb + OWOF + lane * 8;
    const unsigned short* cbase = wsb + OC +
        ((size_t)((b * 72 + nt) * 12)) * 512 + lane * 8;

    f32x16 acc = {};
    #pragma unroll
    for (int j = 0; j < 3; ++j) {
        const unsigned short* cj = cbase + (size_t)j * CSTR;
        #pragma unroll
        for (int ksx = 0; ksx < 12; ++ksx) {
            bf16x8 bx = *(const bf16x8*)(cj + ksx * 512);
            bf16x8 a0 = *(const bf16x8*)(wof + (ksx * 8 + rb) * 512);
            acc = __builtin_amdgcn_mfma_f32_32x32x16_bf16(a0, bx, acc, 0, 0, 0);
        }
    }

    int c0 = rb * 32;
    #pragma unroll
    for (int reg = 0; reg < 16; ++reg) {
        int c = c0 + (reg & 3) + 8 * (reg >> 2) + 4 * h;
        size_t idx = ((size_t)(b * CC + c)) * NN_ + n0 + lq;
        float sg = 1.f / (1.f + EXP2(acc[reg] * -1.44269504f));
        out[idx] = x[idx] * sg;
    }
}

extern "C" void kernel_launch(void* const* d_in, const int* in_sizes, int n_in,
                              void* d_out, int out_size, void* d_ws, size_t ws_size,
                              hipStream_t stream) {
    const float* x  = (const float*)d_in[0];
    const float* wq = (const float*)d_in[1];
    const float* wk = (const float*)d_in[2];
    const float* wv = (const float*)d_in[3];
    const float* wo = (const float*)d_in[4];
    unsigned short* wsb = (unsigned short*)d_ws;
    float* out = (float*)d_out;

    prep_kernel<<<300, 256, 0, stream>>>(x, wq, wk, wv, wo, wsb);
    proj_mfma<<<648, 256, 0, stream>>>(wsb);
    attn_kernel<<<1296, 256, 0, stream>>>(wsb);
    out_mfma<<<576, 256, 0, stream>>>(x, wsb, out);
}